// Round 4
// baseline (561.085 us; speedup 1.0000x reference)
//
#include <hip/hip_runtime.h>
#include <math.h>

// ---------------------------------------------------------------------------
// Fully fused (no d_ws): per-block shfl-parallel build of the 16x16 circuit
// unitary into LDS (verified bit-identical in round 3), then bulk forward.
// Round-3 failure mode was register spill (psi[8][16] etc -> 938 MB of
// scratch HBM traffic, VALUBusy 5.6%). Fix: G=2 per pass x 2 passes,
// working set ~95 VGPRs, zero spill.
// ---------------------------------------------------------------------------

struct cpx { float r, i; };

__device__ inline cpx cmul(cpx a, cpx b) { return {a.r*b.r - a.i*b.i, a.r*b.i + a.i*b.r}; }
__device__ inline cpx cadd(cpx a, cpx b) { return {a.r + b.r, a.i + b.i}; }

template<int BIT>
__device__ inline void apply2(cpx& x, int j, cpx g00, cpx g01, cpx g10, cpx g11) {
  cpx p;
  p.r = __shfl_xor(x.r, BIT, 64);
  p.i = __shfl_xor(x.i, BIT, 64);
  const bool hi = (j & BIT) != 0;
  const cpx ca = hi ? g11 : g00;
  const cpx cb = hi ? g10 : g01;
  x = cadd(cmul(ca, x), cmul(cb, p));
}

template<int CB, int TB>
__device__ inline void cnotg(cpx& x, int j) {
  cpx p;
  p.r = __shfl_xor(x.r, TB, 64);
  p.i = __shfl_xor(x.i, TB, 64);
  if (j & CB) x = p;
}

template<int BIT>
__device__ inline void u3g(cpx& x, int j, float th, float ph, float lm) {
  float st, ct; __sincosf(0.5f * th, &st, &ct);
  float sp, cp; __sincosf(ph, &sp, &cp);
  float sl, cl; __sincosf(lm, &sl, &cl);
  const cpx g00 = { ct, 0.f };
  const cpx g01 = { -cl * st, -sl * st };
  const cpx g10 = {  cp * st,  sp * st };
  const cpx g11 = { (cp*cl - sp*sl) * ct, (sp*cl + cp*sl) * ct };
  apply2<BIT>(x, j, g00, g01, g10, g11);
}

template<int BIT>
__device__ inline void ryg(cpx& x, int j, float t) {
  float s, c; __sincosf(0.5f * t, &s, &c);
  const float pr = __shfl_xor(x.r, BIT, 64);
  const float pi = __shfl_xor(x.i, BIT, 64);
  const float ss = (j & BIT) ? s : -s;
  x.r = fmaf(ss, pr, c * x.r);
  x.i = fmaf(ss, pi, c * x.i);
}

template<int BIT>
__device__ inline void rzg(cpx& x, int j, float t) {
  float s, c; __sincosf(0.5f * t, &s, &c);
  const float ss = (j & BIT) ? s : -s;
  const float nr = fmaf(-ss, x.i, c * x.r);
  const float ni = fmaf( ss, x.r, c * x.i);
  x.r = nr; x.i = ni;
}

template<int A, int B>
__device__ inline void su4g(cpx& x, int j, const float* const* W) {
  constexpr int BA = 8 >> A, BB = 8 >> B;
  u3g<BA>(x, j, W[0][0], W[0][1], W[0][2]);
  u3g<BB>(x, j, W[1][0], W[1][1], W[1][2]);
  cnotg<BA, BB>(x, j);
  ryg<BA>(x, j, W[2][0]);
  rzg<BB>(x, j, W[3][0]);
  cnotg<BB, BA>(x, j);
  ryg<BA>(x, j, W[4][0]);
  cnotg<BA, BB>(x, j);
  u3g<BA>(x, j, W[5][0], W[5][1], W[5][2]);
  u3g<BB>(x, j, W[6][0], W[6][1], W[6][2]);
}

#define BLK    512
#define G      2
#define PASSES 2
// elements per block = BLK * G * PASSES = 2048; grid = B / 2048 = 512

__global__ __launch_bounds__(BLK, 2)
void quanv_fused(const float4* __restrict__ pat,
                 const float* w0,  const float* w1,  const float* w2,
                 const float* w3,  const float* w4,  const float* w5,
                 const float* w6,  const float* w7,  const float* w8,
                 const float* w9,  const float* w10, const float* w11,
                 const float* w12, const float* w13,
                 float4* __restrict__ out, int B) {
  __shared__ float2 Ush[256];   // Ush[k*16 + j] = U[k][j]

  const int tid = threadIdx.x;

  // ---- in-block unitary build: threads 0..255 (waves 0-3), verified r3 ----
  if (tid < 256) {
    const int col = tid >> 4;
    const int j   = tid & 15;
    cpx x = { (j == col) ? 1.f : 0.f, 0.f };
    {
      const float* WA[7] = { w0, w1, w2, w3, w4, w5, w6 };
      su4g<0,1>(x, j, WA); su4g<1,2>(x, j, WA);
      su4g<2,3>(x, j, WA); su4g<3,0>(x, j, WA);
    }
    {
      const float* WB[7] = { w7, w8, w9, w10, w11, w12, w13 };
      su4g<0,1>(x, j, WB); su4g<1,2>(x, j, WB);
      su4g<2,3>(x, j, WB); su4g<3,0>(x, j, WB);
    }
    Ush[j * 16 + col] = make_float2(x.r, x.i);
  }
  __syncthreads();

  const float HPI = 1.5707963267948966f;  // pi/2
  const int blockBase = blockIdx.x * (BLK * G * PASSES);

#pragma unroll 1                 // keep the two passes' live ranges separate
  for (int c = 0; c < PASSES; ++c) {
    const int base = blockBase + c * (BLK * G) + tid;

    float psi[G][16];
    float4 acc[G];
#pragma unroll
    for (int g = 0; g < G; ++g) {
      const int e = base + g * BLK;
      const float4 p = (e < B) ? pat[e] : make_float4(0.f, 0.f, 0.f, 0.f);
      const float h0 = HPI / (1.f + __expf(-p.x));
      const float h1 = HPI / (1.f + __expf(-p.y));
      const float h2 = HPI / (1.f + __expf(-p.z));
      const float h3 = HPI / (1.f + __expf(-p.w));
      float c0, s0, c1, s1, c2, s2, c3, s3;
      __sincosf(h0, &s0, &c0); __sincosf(h1, &s1, &c1);
      __sincosf(h2, &s2, &c2); __sincosf(h3, &s3, &c3);
      const float q01[4] = { c0*c1, c0*s1, s0*c1, s0*s1 };
      const float q23[4] = { c2*c3, c2*s3, s2*c3, s2*s3 };
#pragma unroll
      for (int j = 0; j < 16; ++j) psi[g][j] = q01[j >> 2] * q23[j & 3];
      acc[g] = make_float4(0.f, 0.f, 0.f, 0.f);
    }

#pragma unroll
    for (int k = 0; k < 16; ++k) {
      // row k of U as 8 float4 (16 float2), uniform address -> broadcast
      const float4* __restrict__ rowp = (const float4*)(&Ush[k * 16]);
      float4 q[8];
#pragma unroll
      for (int j2 = 0; j2 < 8; ++j2) q[j2] = rowp[j2];
#pragma unroll
      for (int g = 0; g < G; ++g) {
        float re = 0.f, im = 0.f;
#pragma unroll
        for (int j2 = 0; j2 < 8; ++j2) {
          re = fmaf(q[j2].x, psi[g][2*j2    ], re);
          im = fmaf(q[j2].y, psi[g][2*j2    ], im);
          re = fmaf(q[j2].z, psi[g][2*j2 + 1], re);
          im = fmaf(q[j2].w, psi[g][2*j2 + 1], im);
        }
        const float pr = fmaf(re, re, im * im);
        acc[g].x += (k & 8) ? -pr : pr;
        acc[g].y += (k & 4) ? -pr : pr;
        acc[g].z += (k & 2) ? -pr : pr;
        acc[g].w += (k & 1) ? -pr : pr;
      }
    }

#pragma unroll
    for (int g = 0; g < G; ++g) {
      const int e = base + g * BLK;
      if (e < B) out[e] = acc[g];
    }
  }
}

// ---------------------------------------------------------------------------
extern "C" void kernel_launch(void* const* d_in, const int* in_sizes, int n_in,
                              void* d_out, int out_size, void* d_ws, size_t ws_size,
                              hipStream_t stream) {
  (void)d_ws; (void)ws_size;
  const int B = in_sizes[0] / 4;
  const int blocks = (B + BLK * G * PASSES - 1) / (BLK * G * PASSES);
  quanv_fused<<<blocks, BLK, 0, stream>>>(
      (const float4*)d_in[0],
      (const float*)d_in[1],  (const float*)d_in[2],  (const float*)d_in[3],
      (const float*)d_in[4],  (const float*)d_in[5],  (const float*)d_in[6],
      (const float*)d_in[7],  (const float*)d_in[8],  (const float*)d_in[9],
      (const float*)d_in[10], (const float*)d_in[11], (const float*)d_in[12],
      (const float*)d_in[13], (const float*)d_in[14],
      (float4*)d_out, B);
}

// Round 7
// 119.666 us; speedup vs baseline: 4.6888x; 4.6888x over previous
//
#include <hip/hip_runtime.h>
#include <math.h>

// ---------------------------------------------------------------------------
// Fully fused, zero-array bulk kernel.
//
// History: r2 two-kernel d_ws version: first call passed, post-timing calls
//   diverged -> d_ws structure abandoned.
// r3/r4: fused kernel passed but ran 360-460 us with ~700 MB FETCH / ~550 MB
//   WRITE vs 32 MB ideal: register-spill scratch traffic. VGPR_Count was
//   exactly 128 in both rounds = the cap from __launch_bounds__(512,2)
//   (2 blocks/CU -> 4 waves/SIMD -> 128 regs). Fix here:
//   (a) __launch_bounds__(512,1)  -> 256-reg cap, 2 waves/SIMD;
//   (b) NO local arrays anywhere in the bulk path (all named scalars via
//       macros; rolled k-loop only ever runtime-indexes LDS) -> spilling is
//       structurally impossible (rule #20 hygiene);
//   (c) G=8 elements/thread, 4096 elem/block, 256 blocks = 1 block/CU.
// Gate math + build phase are bit-identical to the silicon-verified r3/r4
// version (absmax 0.0039 vs 0.0185 threshold).
// ---------------------------------------------------------------------------

struct cpx { float r, i; };

__device__ inline cpx cmul(cpx a, cpx b) { return {a.r*b.r - a.i*b.i, a.r*b.i + a.i*b.r}; }
__device__ inline cpx cadd(cpx a, cpx b) { return {a.r + b.r, a.i + b.i}; }

template<int BIT>
__device__ inline void apply2(cpx& x, int j, cpx g00, cpx g01, cpx g10, cpx g11) {
  cpx p;
  p.r = __shfl_xor(x.r, BIT, 64);
  p.i = __shfl_xor(x.i, BIT, 64);
  const bool hi = (j & BIT) != 0;
  const cpx ca = hi ? g11 : g00;
  const cpx cb = hi ? g10 : g01;
  x = cadd(cmul(ca, x), cmul(cb, p));
}

template<int CB, int TB>
__device__ inline void cnotg(cpx& x, int j) {
  cpx p;
  p.r = __shfl_xor(x.r, TB, 64);
  p.i = __shfl_xor(x.i, TB, 64);
  if (j & CB) x = p;
}

template<int BIT>
__device__ inline void u3g(cpx& x, int j, float th, float ph, float lm) {
  float st, ct; __sincosf(0.5f * th, &st, &ct);
  float sp, cp; __sincosf(ph, &sp, &cp);
  float sl, cl; __sincosf(lm, &sl, &cl);
  const cpx g00 = { ct, 0.f };
  const cpx g01 = { -cl * st, -sl * st };
  const cpx g10 = {  cp * st,  sp * st };
  const cpx g11 = { (cp*cl - sp*sl) * ct, (sp*cl + cp*sl) * ct };
  apply2<BIT>(x, j, g00, g01, g10, g11);
}

template<int BIT>
__device__ inline void ryg(cpx& x, int j, float t) {
  float s, c; __sincosf(0.5f * t, &s, &c);
  const float pr = __shfl_xor(x.r, BIT, 64);
  const float pi = __shfl_xor(x.i, BIT, 64);
  const float ss = (j & BIT) ? s : -s;
  x.r = fmaf(ss, pr, c * x.r);
  x.i = fmaf(ss, pi, c * x.i);
}

template<int BIT>
__device__ inline void rzg(cpx& x, int j, float t) {
  float s, c; __sincosf(0.5f * t, &s, &c);
  const float ss = (j & BIT) ? s : -s;
  const float nr = fmaf(-ss, x.i, c * x.r);
  const float ni = fmaf( ss, x.r, c * x.i);
  x.r = nr; x.i = ni;
}

template<int A, int B>
__device__ inline void su4g(cpx& x, int j, const float* const* W) {
  constexpr int BA = 8 >> A, BB = 8 >> B;
  u3g<BA>(x, j, W[0][0], W[0][1], W[0][2]);
  u3g<BB>(x, j, W[1][0], W[1][1], W[1][2]);
  cnotg<BA, BB>(x, j);
  ryg<BA>(x, j, W[2][0]);
  rzg<BB>(x, j, W[3][0]);
  cnotg<BB, BA>(x, j);
  ryg<BA>(x, j, W[4][0]);
  cnotg<BA, BB>(x, j);
  u3g<BA>(x, j, W[5][0], W[5][1], W[5][2]);
  u3g<BB>(x, j, W[6][0], W[6][1], W[6][2]);
}

#define BLK 512
#define G   8
// elements per block = BLK * G = 4096 ; grid = 1048576/4096 = 256 = 1 block/CU

// ---- named-scalar machinery (no arrays -> no scratch, ever) ---------------
#define FORALLG(M) M(0) M(1) M(2) M(3) M(4) M(5) M(6) M(7)
#define FORALLG2(M, jl, jh) M(0,jl,jh) M(1,jl,jh) M(2,jl,jh) M(3,jl,jh) \
                            M(4,jl,jh) M(5,jl,jh) M(6,jl,jh) M(7,jl,jh)

#define DECL_G(g) \
  float ps##g##_0, ps##g##_1, ps##g##_2,  ps##g##_3,  ps##g##_4,  ps##g##_5,  ps##g##_6,  ps##g##_7, \
        ps##g##_8, ps##g##_9, ps##g##_10, ps##g##_11, ps##g##_12, ps##g##_13, ps##g##_14, ps##g##_15; \
  float ax##g = 0.f, ay##g = 0.f, az##g = 0.f, aw##g = 0.f; \
  float re##g, im##g;

#define LOAD_G(g) \
  float4 p##g; \
  { const int e = base + g * BLK; \
    p##g = (e < B) ? pat[e] : make_float4(0.f, 0.f, 0.f, 0.f); }

#define INIT_G(g) { \
  const float h0 = HPI * __builtin_amdgcn_rcpf(1.f + __expf(-p##g.x)); \
  const float h1 = HPI * __builtin_amdgcn_rcpf(1.f + __expf(-p##g.y)); \
  const float h2 = HPI * __builtin_amdgcn_rcpf(1.f + __expf(-p##g.z)); \
  const float h3 = HPI * __builtin_amdgcn_rcpf(1.f + __expf(-p##g.w)); \
  float c0,s0,c1,s1,c2,s2,c3,s3; \
  __sincosf(h0, &s0, &c0); __sincosf(h1, &s1, &c1); \
  __sincosf(h2, &s2, &c2); __sincosf(h3, &s3, &c3); \
  const float a0 = c0*c1, a1 = c0*s1, a2 = s0*c1, a3 = s0*s1; \
  const float b0 = c2*c3, b1 = c2*s3, b2 = s2*c3, b3 = s2*s3; \
  ps##g##_0  = a0*b0; ps##g##_1  = a0*b1; ps##g##_2  = a0*b2; ps##g##_3  = a0*b3; \
  ps##g##_4  = a1*b0; ps##g##_5  = a1*b1; ps##g##_6  = a1*b2; ps##g##_7  = a1*b3; \
  ps##g##_8  = a2*b0; ps##g##_9  = a2*b1; ps##g##_10 = a2*b2; ps##g##_11 = a2*b3; \
  ps##g##_12 = a3*b0; ps##g##_13 = a3*b1; ps##g##_14 = a3*b2; ps##g##_15 = a3*b3; }

// first chunk: multiply (initializes re/im, no zero-init movs)
#define MUL4(g, jl, jh) \
  re##g = qx * ps##g##_##jl;            im##g = qy * ps##g##_##jl; \
  re##g = fmaf(qz, ps##g##_##jh, re##g); im##g = fmaf(qw, ps##g##_##jh, im##g);
// subsequent chunks: accumulate
#define FMA4(g, jl, jh) \
  re##g = fmaf(qx, ps##g##_##jl, re##g); im##g = fmaf(qy, ps##g##_##jl, im##g); \
  re##g = fmaf(qz, ps##g##_##jh, re##g); im##g = fmaf(qw, ps##g##_##jh, im##g);

#define STEP(j2, jl, jh, MM) { \
  const float4 q = rowp[j2]; \
  const float qx = q.x, qy = q.y, qz = q.z, qw = q.w; \
  FORALLG2(MM, jl, jh) }

#define ACC_G(g) { \
  const float pr = fmaf(re##g, re##g, im##g * im##g); \
  ax##g = fmaf(s8, pr, ax##g); ay##g = fmaf(s4, pr, ay##g); \
  az##g = fmaf(s2, pr, az##g); aw##g = fmaf(s1, pr, aw##g); }

#define STORE_G(g) { \
  const int e = base + g * BLK; \
  if (e < B) out[e] = make_float4(ax##g, ay##g, az##g, aw##g); }

__global__ __launch_bounds__(BLK, 1)
void quanv_fused(const float4* __restrict__ pat,
                 const float* w0,  const float* w1,  const float* w2,
                 const float* w3,  const float* w4,  const float* w5,
                 const float* w6,  const float* w7,  const float* w8,
                 const float* w9,  const float* w10, const float* w11,
                 const float* w12, const float* w13,
                 float4* __restrict__ out, int B) {
  __shared__ float4 Ush4[128];   // ((float2*)Ush4)[k*16+j] = U[k][j]

  const int tid  = threadIdx.x;
  const int base = blockIdx.x * (BLK * G) + tid;
  const float HPI = 1.5707963267948966f;  // pi/2

  // ---- issue patch loads early (HBM latency hides under the build) ----
  FORALLG(LOAD_G)

  // ---- in-block unitary build: threads 0..255, silicon-verified (r3/r4) ----
  if (tid < 256) {
    const int col = tid >> 4;
    const int j   = tid & 15;
    cpx x = { (j == col) ? 1.f : 0.f, 0.f };
    {
      const float* WA[7] = { w0, w1, w2, w3, w4, w5, w6 };
      su4g<0,1>(x, j, WA); su4g<1,2>(x, j, WA);
      su4g<2,3>(x, j, WA); su4g<3,0>(x, j, WA);
    }
    {
      const float* WB[7] = { w7, w8, w9, w10, w11, w12, w13 };
      su4g<0,1>(x, j, WB); su4g<1,2>(x, j, WB);
      su4g<2,3>(x, j, WB); su4g<3,0>(x, j, WB);
    }
    ((float2*)Ush4)[j * 16 + col] = make_float2(x.r, x.i);
  }
  __syncthreads();

  // ---- psi0 = product state (named scalars) ----
  FORALLG(DECL_G)
  FORALLG(INIT_G)

  // ---- 16 k-rows: |<k|U|psi0>|^2 with Z-sign accumulation ----
  for (int k = 0; k < 16; ++k) {
    const float4* __restrict__ rowp = &Ush4[k * 8];   // row k = 8 float4
    const float s8 = (k & 8) ? -1.f : 1.f;
    const float s4 = (k & 4) ? -1.f : 1.f;
    const float s2 = (k & 2) ? -1.f : 1.f;
    const float s1 = (k & 1) ? -1.f : 1.f;
    STEP(0,  0,  1, MUL4)
    STEP(1,  2,  3, FMA4)
    STEP(2,  4,  5, FMA4)
    STEP(3,  6,  7, FMA4)
    STEP(4,  8,  9, FMA4)
    STEP(5, 10, 11, FMA4)
    STEP(6, 12, 13, FMA4)
    STEP(7, 14, 15, FMA4)
    FORALLG(ACC_G)
  }

  FORALLG(STORE_G)
}

// ---------------------------------------------------------------------------
extern "C" void kernel_launch(void* const* d_in, const int* in_sizes, int n_in,
                              void* d_out, int out_size, void* d_ws, size_t ws_size,
                              hipStream_t stream) {
  (void)n_in; (void)out_size; (void)d_ws; (void)ws_size;
  const int B = in_sizes[0] / 4;
  const int blocks = (B + BLK * G - 1) / (BLK * G);
  quanv_fused<<<blocks, BLK, 0, stream>>>(
      (const float4*)d_in[0],
      (const float*)d_in[1],  (const float*)d_in[2],  (const float*)d_in[3],
      (const float*)d_in[4],  (const float*)d_in[5],  (const float*)d_in[6],
      (const float*)d_in[7],  (const float*)d_in[8],  (const float*)d_in[9],
      (const float*)d_in[10], (const float*)d_in[11], (const float*)d_in[12],
      (const float*)d_in[13], (const float*)d_in[14],
      (float4*)d_out, B);
}